// Round 9
// baseline (178.686 us; speedup 1.0000x reference)
//
#include <hip/hip_runtime.h>
#include <math.h>

#define BB 4
#define HH 8
#define LL 2048
#define DD 64
#define SK 40            // sample_k == u == 40 for L=2048, FACTOR=5
#define BH (BB*HH)       // 32
#define NG 10            // stage-3 query groups of 4 (descending length)

__device__ __forceinline__ unsigned ordu(float v) {
    unsigned u = __float_as_uint(v);
    return (u & 0x80000000u) ? ~u : (u | 0x80000000u);
}

// ---------------------------------------------------------------------------
// Stage 1: blocks [0,2048) compute M; blocks [2048,2560) compute V chunk sums.
// M layout: 8 lanes/query = 4 chunk-lanes x 2 sample-halves (20 samples each),
// depth-2 pipeline per half -> 4 rows in flight per query, 8192 waves total.
__global__ __launch_bounds__(256) void stage1_kernel(
        const float* __restrict__ Q, const float* __restrict__ K,
        const float* __restrict__ V, const int* __restrict__ IDX,
        float* __restrict__ M, float* __restrict__ csum) {
    int tid = threadIdx.x;
    if (blockIdx.x < 2048) {
        int x = blockIdx.x;
        int bhLo = x & 7;
        int r = x >> 3;                   // [0,256)
        int bhHi = r & 3;
        int chunk = r >> 2;               // [0,64), 32 queries each
        int bh = bhHi * 8 + bhLo;
        int qbase = chunk * 32;
        int w = tid >> 6, lane = tid & 63;
        int c = lane & 3;                 // float4 chunk
        int h = (lane >> 2) & 1;          // sample half
        int qw = lane >> 3;               // query within wave [0,8)
        int qi = w * 8 + qw;              // [0,32)
        int qpos = qbase + qi;

        __shared__ int sidx[32 * SK];     // 5 KB
        for (int i = tid; i < 32 * SK; i += 256) sidx[i] = IDX[(size_t)qbase * SK + i];

        const float4* Q4 = (const float4*)Q;
        const float4* K4 = (const float4*)K;
        float4 qreg[4];
        #pragma unroll
        for (int j = 0; j < 4; ++j)
            qreg[j] = Q4[((size_t)bh * LL + qpos) * 16 + j * 4 + c];
        __syncthreads();

        size_t kb4 = (size_t)bh * LL * 16;
        const int* my = sidx + qi * SK + h * 20;

        int iA = my[0], iB = my[1];
        float4 A[4], B[4];
        #pragma unroll
        for (int j = 0; j < 4; ++j) {
            A[j] = K4[kb4 + (size_t)iA * 16 + j * 4 + c];
            B[j] = K4[kb4 + (size_t)iB * 16 + j * 4 + c];
        }
        int iC = my[2], iD = my[3];

        float mx = -INFINITY, sm = 0.f;
        for (int s = 0; s < 20; s += 2) {
            float4 Cr[4], Dr[4];
            if (s + 2 < 20) {
                #pragma unroll
                for (int j = 0; j < 4; ++j) {
                    Cr[j] = K4[kb4 + (size_t)iC * 16 + j * 4 + c];
                    Dr[j] = K4[kb4 + (size_t)iD * 16 + j * 4 + c];
                }
                if (s + 4 < 20) { iC = my[s + 4]; iD = my[s + 5]; }
            }
            float p0 = 0.f, p1 = 0.f;
            #pragma unroll
            for (int j = 0; j < 4; ++j) {
                p0 += A[j].x * qreg[j].x + A[j].y * qreg[j].y + A[j].z * qreg[j].z + A[j].w * qreg[j].w;
                p1 += B[j].x * qreg[j].x + B[j].y * qreg[j].y + B[j].z * qreg[j].z + B[j].w * qreg[j].w;
            }
            p0 += __shfl_xor(p0, 1, 64);
            p0 += __shfl_xor(p0, 2, 64);
            p1 += __shfl_xor(p1, 1, 64);
            p1 += __shfl_xor(p1, 2, 64);
            mx = fmaxf(mx, fmaxf(p0, p1));
            sm += p0 + p1;
            #pragma unroll
            for (int j = 0; j < 4; ++j) { A[j] = Cr[j]; B[j] = Dr[j]; }
        }
        // merge the two sample-halves (lanes differing in bit 2)
        mx = fmaxf(mx, __shfl_xor(mx, 4, 64));
        sm += __shfl_xor(sm, 4, 64);
        if ((lane & 7) == 0) M[(size_t)bh * LL + qpos] = mx - sm * (1.0f / (float)LL);
    } else {
        // ----- vsum: per-(bh,chunk-of-128) column sums of V
        int x = blockIdx.x - 2048;        // [0,512)
        int bhLo = x & 7, r = x >> 3;
        int bhHi = r & 3, c = r >> 2;     // c in [0,16)
        int bh = bhHi * 8 + bhLo;
        int d = tid & 63, sg = tid >> 6;
        size_t base = (size_t)bh * LL * DD;
        int row0 = c * 128 + sg * 32;
        float s = 0.f;
        for (int j = 0; j < 32; ++j) s += V[base + (size_t)(row0 + j) * DD + d];
        __shared__ float part[4][DD];
        part[sg][d] = s;
        __syncthreads();
        if (sg == 0)
            csum[((size_t)bh * 16 + c) * DD + d] = part[0][d] + part[1][d] + part[2][d] + part[3][d];
    }
}

// ---------------------------------------------------------------------------
// Stage 2: blocks [0,512) cumsum V -> out; blocks [512,544) radix top-40 of M,
// emitted DESCENDING by qpos (stage-3 groups need similar lengths).
__global__ __launch_bounds__(256) void stage2_kernel(
        const float* __restrict__ V, const float* __restrict__ csum,
        const float* __restrict__ M, float* __restrict__ out,
        int* __restrict__ topk) {
    int tid = threadIdx.x;
    if (blockIdx.x < 512) {
        // ----- cumsum
        int x = blockIdx.x;
        int bhLo = x & 7, r = x >> 3;
        int bhHi = r & 3, c = r >> 2;
        int bh = bhHi * 8 + bhLo;
        int d = tid & 63, sg = tid >> 6;
        size_t base = (size_t)bh * LL * DD;
        int row0 = c * 128 + sg * 32;
        float v[32];
        #pragma unroll
        for (int j = 0; j < 32; ++j) v[j] = V[base + (size_t)(row0 + j) * DD + d];
        float s = 0.f;
        #pragma unroll
        for (int j = 0; j < 32; ++j) s += v[j];
        __shared__ float part[4][DD];
        part[sg][d] = s;
        __syncthreads();
        float pre = 0.f;
        for (int cc = 0; cc < c; ++cc) pre += csum[((size_t)bh * 16 + cc) * DD + d];
        for (int ss = 0; ss < sg; ++ss) pre += part[ss][d];
        float acc = pre;
        #pragma unroll
        for (int j = 0; j < 32; ++j) {
            acc += v[j];
            out[base + (size_t)(row0 + j) * DD + d] = acc;
        }
    } else {
        // ----- radix top-40 (8 bits/pass, 4 passes); then sort desc by index.
        int bh = blockIdx.x - 512;
        __shared__ unsigned hist[256];
        __shared__ unsigned bc_prefix, bc_need;
        __shared__ unsigned cnt_gt, cnt_eq;
        __shared__ int eqlist[128];
        __shared__ int sel[SK];

        unsigned v[8];
        #pragma unroll
        for (int j = 0; j < 8; ++j)
            v[j] = ordu(M[(size_t)bh * LL + tid + j * 256]);

        unsigned prefix = 0, need = SK;
        #pragma unroll
        for (int pass = 0; pass < 4; ++pass) {
            const int s = 24 - 8 * pass;
            const unsigned maskHigh = (pass == 0) ? 0u : (0xFFFFFFFFu << (s + 8));
            hist[tid] = 0;
            __syncthreads();
            #pragma unroll
            for (int j = 0; j < 8; ++j)
                if (((v[j] ^ prefix) & maskHigh) == 0)
                    atomicAdd(&hist[(v[j] >> s) & 0xFF], 1u);
            __syncthreads();
            unsigned above = 0;
            for (int b = tid + 1; b < 256; ++b) above += hist[b];
            if (above < need && above + hist[tid] >= need) {
                bc_prefix = prefix | ((unsigned)tid << s);
                bc_need = need - above;
            }
            __syncthreads();
            prefix = bc_prefix;
            need = bc_need;
            __syncthreads();
        }
        unsigned T = prefix;
        if (tid == 0) { cnt_gt = 0; cnt_eq = 0; }
        __syncthreads();
        #pragma unroll
        for (int j = 0; j < 8; ++j) {
            int idx = tid + j * 256;
            if (v[j] > T) { unsigned p = atomicAdd(&cnt_gt, 1u); sel[p] = idx; }
            else if (v[j] == T) { unsigned p = atomicAdd(&cnt_eq, 1u); if (p < 128) eqlist[p] = idx; }
        }
        __syncthreads();
        if (tid == 0) {
            int ne = (int)min(cnt_eq, 128u);
            unsigned base = cnt_gt;       // == SK - need
            for (unsigned r2 = 0; r2 < need; ++r2) {
                int bj = 0, bv = 0x7FFFFFFF;
                for (int j = 0; j < ne; ++j)
                    if (eqlist[j] < bv) { bv = eqlist[j]; bj = j; }
                sel[base + r2] = bv;
                eqlist[bj] = 0x7FFFFFFF;
            }
        }
        __syncthreads();
        // rank-sort descending by qpos (indices distinct): longest rows first
        if (tid < SK) {
            int mine = sel[tid];
            int rank = 0;
            #pragma unroll
            for (int j = 0; j < SK; ++j) rank += (sel[j] > mine);
            topk[bh * SK + rank] = mine;
        }
    }
}

// ---------------------------------------------------------------------------
// Stage 3: one block per (bh, group of 4 sorted u's). Each K/V row load feeds
// 4 queries (4 dots / 64 FMA per 64 B). Two-pass softmax per query over
// sc[4][nk] in LDS; causal mask via -inf at score time. Direct output write.
__global__ __launch_bounds__(256) void attn_kernel(
        const float* __restrict__ Q, const float* __restrict__ K,
        const float* __restrict__ V, const int* __restrict__ topk,
        float* __restrict__ out) {
    int x = blockIdx.x;               // 320
    int bh = x & 31;                  // XCD spread; same-bh groups same XCD
    int g = x >> 5;                   // [0,10), ascending = longest-first
    int tid = threadIdx.x;

    int qp[4];
    #pragma unroll
    for (int i = 0; i < 4; ++i) qp[i] = topk[bh * SK + g * 4 + i];
    int nk = qp[0] + 1;               // descending within group -> qp[0] max

    const float4* Q4 = (const float4*)Q;
    const float4* K4 = (const float4*)K;
    const float4* V4 = (const float4*)V;

    int w = tid >> 6, lane = tid & 63;
    int c = lane & 3, kw = lane >> 2; // 4 lanes/key, 16 keys/wave-round

    float4 qreg[4][4];
    #pragma unroll
    for (int i = 0; i < 4; ++i)
        #pragma unroll
        for (int j = 0; j < 4; ++j)
            qreg[i][j] = Q4[((size_t)bh * LL + qp[i]) * 16 + j * 4 + c];

    __shared__ float sc[4][LL];       // 32 KB
    __shared__ float red[4][4], red2[4][4];
    __shared__ float opart[16][16][4];

    // ---- score phase: 64 keys per block-round, 4 dots per row load
    size_t kb4 = (size_t)bh * LL * 16;
    int rounds = (nk + 63) >> 6;
    for (int rr = 0; rr < rounds; ++rr) {
        int key = rr * 64 + w * 16 + kw;
        if (key < nk) {
            float4 A[4];
            #pragma unroll
            for (int j = 0; j < 4; ++j) A[j] = K4[kb4 + (size_t)key * 16 + j * 4 + c];
            float p0 = 0.f, p1 = 0.f, p2 = 0.f, p3 = 0.f;
            #pragma unroll
            for (int j = 0; j < 4; ++j) {
                p0 += A[j].x * qreg[0][j].x + A[j].y * qreg[0][j].y + A[j].z * qreg[0][j].z + A[j].w * qreg[0][j].w;
                p1 += A[j].x * qreg[1][j].x + A[j].y * qreg[1][j].y + A[j].z * qreg[1][j].z + A[j].w * qreg[1][j].w;
                p2 += A[j].x * qreg[2][j].x + A[j].y * qreg[2][j].y + A[j].z * qreg[2][j].z + A[j].w * qreg[2][j].w;
                p3 += A[j].x * qreg[3][j].x + A[j].y * qreg[3][j].y + A[j].z * qreg[3][j].z + A[j].w * qreg[3][j].w;
            }
            p0 += __shfl_xor(p0, 1, 64); p0 += __shfl_xor(p0, 2, 64);
            p1 += __shfl_xor(p1, 1, 64); p1 += __shfl_xor(p1, 2, 64);
            p2 += __shfl_xor(p2, 1, 64); p2 += __shfl_xor(p2, 2, 64);
            p3 += __shfl_xor(p3, 1, 64); p3 += __shfl_xor(p3, 2, 64);
            if (c == 0) {
                sc[0][key] = (key <= qp[0]) ? p0 * 0.125f : -INFINITY;
                sc[1][key] = (key <= qp[1]) ? p1 * 0.125f : -INFINITY;
                sc[2][key] = (key <= qp[2]) ? p2 * 0.125f : -INFINITY;
                sc[3][key] = (key <= qp[3]) ? p3 * 0.125f : -INFINITY;
            }
        }
    }
    __syncthreads();

    // ---- max per query
    float m[4] = {-INFINITY, -INFINITY, -INFINITY, -INFINITY};
    for (int j = tid; j < nk; j += 256) {
        #pragma unroll
        for (int i = 0; i < 4; ++i) m[i] = fmaxf(m[i], sc[i][j]);
    }
    #pragma unroll
    for (int i = 0; i < 4; ++i) {
        float mv = m[i];
        #pragma unroll
        for (int off = 32; off > 0; off >>= 1) mv = fmaxf(mv, __shfl_xor(mv, off, 64));
        if (lane == 0) red[w][i] = mv;
        m[i] = mv;
    }
    __syncthreads();
    #pragma unroll
    for (int i = 0; i < 4; ++i)
        m[i] = fmaxf(fmaxf(red[0][i], red[1][i]), fmaxf(red[2][i], red[3][i]));

    // ---- exp + sum per query
    float l[4] = {0.f, 0.f, 0.f, 0.f};
    for (int j = tid; j < nk; j += 256) {
        #pragma unroll
        for (int i = 0; i < 4; ++i) {
            float e = expf(sc[i][j] - m[i]);   // -inf -> 0
            sc[i][j] = e;
            l[i] += e;
        }
    }
    #pragma unroll
    for (int i = 0; i < 4; ++i) {
        float lv = l[i];
        #pragma unroll
        for (int off = 32; off > 0; off >>= 1) lv += __shfl_xor(lv, off, 64);
        if (lane == 0) red2[w][i] = lv;
    }
    __syncthreads();
    float linv[4];
    #pragma unroll
    for (int i = 0; i < 4; ++i)
        linv[i] = 1.0f / (red2[0][i] + red2[1][i] + red2[2][i] + red2[3][i]);

    // ---- PV: each V row load feeds 4 accumulators
    int col4 = tid & 15, kg = tid >> 4;
    float4 acc[4];
    #pragma unroll
    for (int i = 0; i < 4; ++i) acc[i] = make_float4(0.f, 0.f, 0.f, 0.f);
    size_t vb4 = (size_t)bh * LL * 16;
    for (int j = kg; j < nk; j += 16) {
        float4 vv = V4[vb4 + (size_t)j * 16 + col4];
        #pragma unroll
        for (int i = 0; i < 4; ++i) {
            float sj = sc[i][j];
            acc[i].x += sj * vv.x; acc[i].y += sj * vv.y;
            acc[i].z += sj * vv.z; acc[i].w += sj * vv.w;
        }
    }
    #pragma unroll
    for (int i = 0; i < 4; ++i) {
        opart[kg][col4][0] = acc[i].x;
        opart[kg][col4][1] = acc[i].y;
        opart[kg][col4][2] = acc[i].z;
        opart[kg][col4][3] = acc[i].w;
        __syncthreads();
        if (tid < DD) {
            int c4 = tid >> 2, cp = tid & 3;
            float s = 0.f;
            #pragma unroll
            for (int kg2 = 0; kg2 < 16; ++kg2) s += opart[kg2][c4][cp];
            out[((size_t)bh * LL + qp[i]) * DD + tid] = s * linv[i];
        }
        __syncthreads();
    }
}

// ---------------------------------------------------------------------------
extern "C" void kernel_launch(void* const* d_in, const int* in_sizes, int n_in,
                              void* d_out, int out_size, void* d_ws, size_t ws_size,
                              hipStream_t stream) {
    const float* Q   = (const float*)d_in[0];
    const float* K   = (const float*)d_in[1];
    const float* V   = (const float*)d_in[2];
    const int*   IDX = (const int*)d_in[3];
    float* out = (float*)d_out;

    char* ws = (char*)d_ws;
    float* M    = (float*)ws;  ws += (size_t)BH * LL * sizeof(float);                 // 256 KB
    int*   topk = (int*)ws;    ws += ((size_t)BH * SK * sizeof(int) + 255) & ~255ull;
    float* csum = (float*)ws;  // BH*16*DD floats = 128 KB

    stage1_kernel<<<2560, 256, 0, stream>>>(Q, K, V, IDX, M, csum);
    stage2_kernel<<<544, 256, 0, stream>>>(V, csum, M, out, topk);
    attn_kernel<<<BH * NG, 256, 0, stream>>>(Q, K, V, topk, out);
}